// Round 1
// baseline (341.245 us; speedup 1.0000x reference)
//
#include <hip/hip_runtime.h>
#include <math.h>

namespace {

constexpr int H = 2048;
constexpr int W = 2048;
constexpr float TANH_C  = 1.1486328125f;
constexpr float DEG2RAD = 0.017453292519943295f; // rounds to np.float32(pi/180)

// out layout: [0,HW) p_ignite (f32), [HW,2HW) new_burning (0/1 f32), [2HW,3HW) new_burned
__global__ __launch_bounds__(256) void wildfire_step(
    const float* __restrict__ p_veg,  const float* __restrict__ p_den,
    const float* __restrict__ wind_v, const float* __restrict__ wind_d,
    const float* __restrict__ slope,
    const float* __restrict__ s_a,  const float* __restrict__ s_ph,
    const float* __restrict__ s_c1, const float* __restrict__ s_c2,
    const float* __restrict__ s_pc,
    const float* __restrict__ rand_ig, const float* __restrict__ rand_co,
    const int* __restrict__ burning, const int* __restrict__ burned,
    float* __restrict__ out)
{
    __shared__ float sb[3][260];           // burning halo: rows i-1..i+1, cols j0-1..j0+256
    const int t  = (int)threadIdx.x;
    const int i  = (int)blockIdx.y;
    const int j0 = (int)blockIdx.x * 256;
    const int j  = j0 + t;

    for (int r = 0; r < 3; ++r) {
        const int ii = i + r - 1;
        for (int c = t; c < 258; c += 256) {
            const int jj = j0 - 1 + c;
            float v = 0.f;
            if (ii >= 0 && ii < H && jj >= 0 && jj < W)
                v = burning[ii * W + jj] ? 1.f : 0.f;
            sb[r][c] = v;
        }
    }
    __syncthreads();

    // 3x3 burning window for this cell (window pos (r,c) -> slope index r*3+c)
    const float b0 = sb[0][t], b1 = sb[0][t+1], b2 = sb[0][t+2];
    const float b3 = sb[1][t], bc = sb[1][t+1], b5 = sb[1][t+2];
    const float b6 = sb[2][t], b7 = sb[2][t+1], b8 = sb[2][t+2];

    const int   idx       = i * W + j;
    const bool  is_burning = (bc != 0.f);
    const int   was_burned = burned[idx];
    const float rco        = rand_co[idx];
    const float p_cont     = s_pc[0];

    const float any_n = b0 + b1 + b2 + b3 + b5 + b6 + b7 + b8;

    float p_ignite   = 0.f;
    bool  new_ignited = false;

    if (__any(any_n != 0.f)) {              // wave-uniform heavy path (~86% of waves)
        const float a   = s_a[0];
        const float p_h = s_ph[0];
        const float c1  = s_c1[0];
        const float c2  = s_c2[0];
        const float pv  = p_veg[idx];
        const float pd  = p_den[idx];
        const float wv  = wind_v[idx];
        const float wd  = wind_d[idx];

        const float ew     = expf(c1 * wv);            // shared wind factor (ref computes once)
        const float cvw    = c2 * wv;
        const float p_base = (p_h * (1.f + pv)) * (1.f + pd);
        const float* sl    = slope + (size_t)idx * 9;

        // product in reference order (row-major over the 3x3 window, center factor == 1)
        float prod = 1.f;
#define NEIGHBOR(bk, dirdeg, si)                                           \
        if (__any(bk != 0.f)) {                                            \
            const float ct = cosf((wd - dirdeg) * DEG2RAD);                \
            const float pw = ew * expf(cvw * (ct - 1.f));                  \
            const float ps = expf((a * sl[si]) * DEG2RAD);                 \
            const float pp = tanhf(TANH_C * ((p_base * pw) * ps));         \
            prod *= 1.f - pp * bk;                                         \
        }
        NEIGHBOR(b0, 315.f, 0)
        NEIGHBOR(b1, 270.f, 1)
        NEIGHBOR(b2, 225.f, 2)
        NEIGHBOR(b3,   0.f, 3)
        NEIGHBOR(b5, 180.f, 5)
        NEIGHBOR(b6,  45.f, 6)
        NEIGHBOR(b7,  90.f, 7)
        NEIGHBOR(b8, 135.f, 8)
#undef NEIGHBOR
        p_ignite = 1.f - prod;

        const float rig = rand_ig[idx];
        new_ignited = (!is_burning) && (was_burned == 0) && (rig < p_ignite);
    }

    const bool keep = is_burning && (rco < p_cont);
    const bool nb   = new_ignited || keep;
    const bool nd   = (was_burned != 0) || (is_burning && !keep);

    out[idx]             = p_ignite;
    out[H * W + idx]     = nb ? 1.f : 0.f;
    out[2 * H * W + idx] = nd ? 1.f : 0.f;
}

} // namespace

extern "C" void kernel_launch(void* const* d_in, const int* in_sizes, int n_in,
                              void* d_out, int out_size, void* d_ws, size_t ws_size,
                              hipStream_t stream)
{
    (void)in_sizes; (void)n_in; (void)out_size; (void)d_ws; (void)ws_size;
    dim3 grid(W / 256, H, 1);
    dim3 block(256, 1, 1);
    hipLaunchKernelGGL(wildfire_step, grid, block, 0, stream,
        (const float*)d_in[0],  (const float*)d_in[1],
        (const float*)d_in[2],  (const float*)d_in[3],
        (const float*)d_in[4],
        (const float*)d_in[5],  (const float*)d_in[6],
        (const float*)d_in[7],  (const float*)d_in[8],
        (const float*)d_in[9],
        (const float*)d_in[10], (const float*)d_in[11],
        (const int*)d_in[12],   (const int*)d_in[13],
        (float*)d_out);
}

// Round 2
// 326.945 us; speedup vs baseline: 1.0437x; 1.0437x over previous
//
#include <hip/hip_runtime.h>
#include <math.h>

namespace {

constexpr int H = 2048;
constexpr int W = 2048;
constexpr float TANH_C  = 1.1486328125f;
constexpr float DEG2RAD = 0.017453292519943295f; // == np.float32(pi/180)
constexpr float RT2H    = 0.70710678118654752f;  // sqrt(2)/2

// out layout: [0,HW) p_ignite, [HW,2HW) new_burning (0/1), [2HW,3HW) new_burned
__global__ __launch_bounds__(256) void wildfire_step(
    const float* __restrict__ p_veg,  const float* __restrict__ p_den,
    const float* __restrict__ wind_v, const float* __restrict__ wind_d,
    const float* __restrict__ slope,
    const float* __restrict__ s_a,  const float* __restrict__ s_ph,
    const float* __restrict__ s_c1, const float* __restrict__ s_c2,
    const float* __restrict__ s_pc,
    const float* __restrict__ rand_ig, const float* __restrict__ rand_co,
    const int* __restrict__ burning, const int* __restrict__ burned,
    float* __restrict__ out)
{
    __shared__ float sb[3][260];           // burning halo: rows i-1..i+1, cols j0-1..j0+256
    const int t  = (int)threadIdx.x;
    const int i  = (int)blockIdx.y;
    const int j0 = (int)blockIdx.x * 256;
    const int j  = j0 + t;

    for (int r = 0; r < 3; ++r) {
        const int ii = i + r - 1;
        for (int c = t; c < 258; c += 256) {
            const int jj = j0 - 1 + c;
            float v = 0.f;
            if (ii >= 0 && ii < H && jj >= 0 && jj < W)
                v = burning[ii * W + jj] ? 1.f : 0.f;
            sb[r][c] = v;
        }
    }
    __syncthreads();

    // 3x3 burning window (window pos (r,c) -> slope index r*3+c)
    const float b0 = sb[0][t], b1 = sb[0][t+1], b2 = sb[0][t+2];
    const float b3 = sb[1][t], bc = sb[1][t+1], b5 = sb[1][t+2];
    const float b6 = sb[2][t], b7 = sb[2][t+1], b8 = sb[2][t+2];

    const int   idx        = i * W + j;
    const bool  is_burning = (bc != 0.f);
    const int   was_burned = burned[idx];
    const float rco        = rand_co[idx];
    const float p_cont     = s_pc[0];

    const float any_n = b0 + b1 + b2 + b3 + b5 + b6 + b7 + b8;

    float p_ignite    = 0.f;
    bool  new_ignited = false;

    if (__any(any_n != 0.f)) {              // wave-uniform heavy path (~86% of waves)
        // ---- hoisted independent loads ----
        const float pv  = p_veg[idx];
        const float pd  = p_den[idx];
        const float wv  = wind_v[idx];
        const float wd  = wind_d[idx];
        const float rig = rand_ig[idx];
        float sl[9];
        __builtin_memcpy(sl, slope + (size_t)idx * 9, 9 * sizeof(float));

        const float a   = s_a[0];
        const float p_h = s_ph[0];
        const float c1  = s_c1[0];
        const float c2  = s_c2[0];

        // per-cell transcendentals (3 total)
        const float wr  = wd * DEG2RAD;
        const float cw  = cosf(wr);
        const float sw  = sinf(wr);
        const float ew  = expf(c1 * wv);
        const float cvw = c2 * wv;
        const float asl = a * DEG2RAD;
        const float p_base = (p_h * (1.f + pv)) * (1.f + pd);
        const float Cz  = TANH_C * (p_base * ew);

        // pp_k = tanh(z_k), z_k = Cz * exp(cvw*(ct_k-1) + asl*sl_k)
        // factor_k = 1 - pp_k*b_k = b_k ? 2/(E_k+1) : 1, E_k = exp(2 z_k)
        // => p_ignite = 1 - 2^m / prod(b_k ? E_k+1 : 1)   (one division total)
#define NEIGHBOR(K, b, CK, SK, si)                                          \
        const float ct##K = fmaf(cw, (CK), sw * (SK));                      \
        const float u##K  = fmaf(cvw, ct##K - 1.f, asl * sl[si]);           \
        const float z##K  = Cz * expf(u##K);                                \
        const float E##K  = expf(z##K + z##K);                              \
        const float d##K  = ((b) != 0.f) ? (E##K + 1.f) : 1.f;              \
        const float n##K  = ((b) != 0.f) ? 2.f : 1.f;

        NEIGHBOR(0, b0,  RT2H, -RT2H, 0)   // 315
        NEIGHBOR(1, b1,  0.f,  -1.f,  1)   // 270
        NEIGHBOR(2, b2, -RT2H, -RT2H, 2)   // 225
        NEIGHBOR(3, b3,  1.f,   0.f,  3)   //   0
        NEIGHBOR(5, b5, -1.f,   0.f,  5)   // 180
        NEIGHBOR(6, b6,  RT2H,  RT2H, 6)   //  45
        NEIGHBOR(7, b7,  0.f,   1.f,  7)   //  90
        NEIGHBOR(8, b8, -RT2H,  RT2H, 8)   // 135
#undef NEIGHBOR
        const float den = ((d0 * d1) * (d2 * d3)) * ((d5 * d6) * (d7 * d8));
        const float num = ((n0 * n1) * (n2 * n3)) * ((n5 * n6) * (n7 * n8));
        p_ignite = 1.f - num / den;

        new_ignited = (!is_burning) && (was_burned == 0) && (rig < p_ignite);
    }

    const bool keep = is_burning && (rco < p_cont);
    const bool nb   = new_ignited || keep;
    const bool nd   = (was_burned != 0) || (is_burning && !keep);

    out[idx]             = p_ignite;
    out[H * W + idx]     = nb ? 1.f : 0.f;
    out[2 * H * W + idx] = nd ? 1.f : 0.f;
}

} // namespace

extern "C" void kernel_launch(void* const* d_in, const int* in_sizes, int n_in,
                              void* d_out, int out_size, void* d_ws, size_t ws_size,
                              hipStream_t stream)
{
    (void)in_sizes; (void)n_in; (void)out_size; (void)d_ws; (void)ws_size;
    dim3 grid(W / 256, H, 1);
    dim3 block(256, 1, 1);
    hipLaunchKernelGGL(wildfire_step, grid, block, 0, stream,
        (const float*)d_in[0],  (const float*)d_in[1],
        (const float*)d_in[2],  (const float*)d_in[3],
        (const float*)d_in[4],
        (const float*)d_in[5],  (const float*)d_in[6],
        (const float*)d_in[7],  (const float*)d_in[8],
        (const float*)d_in[9],
        (const float*)d_in[10], (const float*)d_in[11],
        (const int*)d_in[12],   (const int*)d_in[13],
        (float*)d_out);
}